// Round 9
// baseline (564.916 us; speedup 1.0000x reference)
//
#include <hip/hip_runtime.h>
#include <hip/hip_bf16.h>

#define NEG_SLOPE 0.2f
#define NBLOCKS   2048
#define NLINES    16
#define PER_LINE  (NBLOCKS / NLINES)   // 128

typedef float f32x4 __attribute__((ext_vector_type(4)));

// bf16 helpers (RTN-even pack, shift-unpack)
__device__ __forceinline__ unsigned f2bf(float f) {
    unsigned u = __float_as_uint(f);
    return (u + 0x7FFFu + ((u >> 16) & 1u)) >> 16;
}
__device__ __forceinline__ float bf2f(unsigned h) {
    return __uint_as_float(h << 16);
}

// ---------------------------------------------------------------------------
// Grid barrier: 2048 co-resident blocks (8/CU by construction: 256 thr, no
// LDS, <=64 VGPR via launch_bounds). Arrivals spread over 16 cache lines
// (64 B apart) to cut same-line atomic serialization ~16x. Release/acquire at
// AGENT scope: release publishes prior plain stores (L2 writeback), acquire
// invalidates stale cached lines before subsequent plain loads (G16).
// ---------------------------------------------------------------------------
__device__ __forceinline__ void grid_barrier(unsigned* base) {
    __syncthreads();
    if (threadIdx.x == 0) {
        unsigned* c = base + (blockIdx.x & (NLINES - 1)) * 16;  // 16 u32 = 64 B stride
        __hip_atomic_fetch_add(c, 1u, __ATOMIC_RELEASE, __HIP_MEMORY_SCOPE_AGENT);
    }
    if (threadIdx.x < NLINES) {
        unsigned* c = base + threadIdx.x * 16;
        while (__hip_atomic_load(c, __ATOMIC_ACQUIRE, __HIP_MEMORY_SCOPE_AGENT)
               < (unsigned)PER_LINE) {
            __builtin_amdgcn_s_sleep(2);
        }
    }
    __syncthreads();
}

// ---------------------------------------------------------------------------
// Folded 64-lane reduction (6 shuffles) — proven R5.
// ---------------------------------------------------------------------------
__device__ __forceinline__ float fold_reduce(float sib, float sjb,
                                             float sip, float sjp,
                                             bool hiB, bool hiJ) {
    float g1 = hiB ? sib : sip;
    float r1 = __shfl_xor(g1, 16);
    float acc_i = (hiB ? sip : sib) + r1;
    float g2 = hiB ? sjb : sjp;
    float r2 = __shfl_xor(g2, 16);
    float acc_j = (hiB ? sjp : sjb) + r2;
    float g3 = hiJ ? acc_i : acc_j;
    float r3 = __shfl_xor(g3, 8);
    float acc = (hiJ ? acc_j : acc_i) + r3;
    acc += __shfl_xor(acc, 4);
    acc += __shfl_xor(acc, 2);
    acc += __shfl_xor(acc, 1);
    return acc;
}

__device__ __forceinline__ float dot4(const f32x4 z, const f32x4 v) {
    return z.x * v.x + z.y * v.y + z.z * v.z + z.w * v.w;
}

__device__ __forceinline__ void pack_store(float acc, int c, bool valid,
                                           uint2* __restrict__ tab8, int node) {
    const float a1 = __shfl_down(acc, 8);
    const float a2 = __shfl_down(acc, 16);
    const float a3 = __shfl_down(acc, 24);
    if (c == 0 && valid) {
        uint2 p;
        p.x = f2bf(acc) | (f2bf(a1) << 16);
        p.y = f2bf(a2) | (f2bf(a3) << 16);
        tab8[node] = p;
    }
}

__device__ __forceinline__ float lrelu(float x) {
    return x >= 0.f ? x : NEG_SLOPE * x;
}

__device__ __forceinline__ float edge_score8(const uint2 ts, const uint2 td,
                                             float w0, float w1) {
    const float s_ib = bf2f(ts.x & 0xFFFFu), s_jb = bf2f(ts.x >> 16);
    const float s_ip = bf2f(ts.y & 0xFFFFu), s_jp = bf2f(ts.y >> 16);
    const float d_ib = bf2f(td.x & 0xFFFFu), d_jb = bf2f(td.x >> 16);
    const float d_ip = bf2f(td.y & 0xFFFFu), d_jp = bf2f(td.y >> 16);
    const float sb = 0.5f * (lrelu(s_ib + d_jb) + lrelu(d_ib + s_jb));
    const float sp = 0.5f * (lrelu(s_ip + d_jp) + lrelu(d_ip + s_jp));
    const float sc = w0 * sb + w1 * sp;            // TAU_MRF == 1
    return 1.f / (1.f + __expf(-sc));
}

// ---------------------------------------------------------------------------
// Single fused kernel: [block0: v-fold] -> barrierA -> node phase -> fence ->
// barrierB -> edge phase.  Workspace: [0,2KB) barrier counters (memset 0 per
// launch), [4KB,6KB) v, [8KB,...) tab8.
// ---------------------------------------------------------------------------
__global__ void __launch_bounds__(256, 8) fused_all_kernel(
        const float* __restrict__ W_b,
        const float* __restrict__ W_p,
        const float* __restrict__ a_b,
        const float* __restrict__ a_p,
        const f32x4* __restrict__ zb4,
        const f32x4* __restrict__ zp4,
        const int*   __restrict__ src,
        const int*   __restrict__ dst,
        const float* __restrict__ gamma_b,
        const float* __restrict__ gamma_p,
        float*       __restrict__ out,
        unsigned*    __restrict__ ws_barrier,   // 2 x 1KB
        float*       __restrict__ vws,          // 512 floats
        uint2*       __restrict__ tab8,
        int n_nodes, int n_edges) {
    const int tid = threadIdx.x;

    // ---- phase 0: block 0 folds v = W^T a (others fall through to barrier)
    if (blockIdx.x == 0) {
        const int p  = tid & 127;
        const int ch = tid >> 7;
        const float* W = ch ? W_p : W_b;
        const float* a = ch ? a_p : a_b;
        float acc1 = 0.f, acc2 = 0.f;
        #pragma unroll
        for (int d = 0; d < 64; ++d) {
            const float w = W[d * 128 + p];
            acc1 += w * a[d];
            acc2 += w * a[64 + d];
        }
        vws[(2 * ch + 0) * 128 + p] = acc1;
        vws[(2 * ch + 1) * 128 + p] = acc2;
        __threadfence();   // publish v before arrival (agent-scope writeback)
    }
    grid_barrier(ws_barrier);          // barrier A: v ready

    // ---- node phase (R6-proven 2-pair loop) ----
    {
        const int lane = tid & 63;
        const int h    = lane >> 5;
        const int c    = lane & 31;
        const int wave   = (blockIdx.x * blockDim.x + tid) >> 6;
        const int nwaves = (gridDim.x * blockDim.x) >> 6;   // 8192
        const int npairs = (n_nodes + 1) >> 1;

        const f32x4 v1b = *reinterpret_cast<const f32x4*>(vws + 0 * 128 + 4 * c);
        const f32x4 v2b = *reinterpret_cast<const f32x4*>(vws + 1 * 128 + 4 * c);
        const f32x4 v1p = *reinterpret_cast<const f32x4*>(vws + 2 * 128 + 4 * c);
        const f32x4 v2p = *reinterpret_cast<const f32x4*>(vws + 3 * 128 + 4 * c);

        const bool hiB = (c & 16) != 0;
        const bool hiJ = (c & 8)  != 0;

        for (int pr = wave; pr < npairs; pr += 2 * nwaves) {
            const int pr2 = pr + nwaves;
            int node1 = 2 * pr + h;
            const bool valid1 = node1 < n_nodes;
            if (!valid1) node1 = n_nodes - 1;
            const f32x4 zb1 = zb4[(size_t)node1 * 32 + c];
            const f32x4 zp1 = zp4[(size_t)node1 * 32 + c];
            int node2 = 2 * pr2 + h;
            const bool run2 = pr2 < npairs;
            bool valid2 = run2 && (node2 < n_nodes);
            if (!valid2) node2 = n_nodes - 1;
            const f32x4 zb2 = zb4[(size_t)node2 * 32 + c];
            const f32x4 zp2 = zp4[(size_t)node2 * 32 + c];

            float acc1 = fold_reduce(dot4(zb1, v1b), dot4(zb1, v2b),
                                     dot4(zp1, v1p), dot4(zp1, v2p), hiB, hiJ);
            pack_store(acc1, c, valid1, tab8, node1);

            float acc2 = fold_reduce(dot4(zb2, v1b), dot4(zb2, v2b),
                                     dot4(zp2, v1p), dot4(zp2, v2p), hiB, hiJ);
            pack_store(acc2, c, valid2, tab8, node2);
        }
    }

    __threadfence();                   // publish tab8 (agent-scope writeback)
    grid_barrier(ws_barrier + 256);    // barrier B: tab8 ready (offset 1 KB)

    // ---- edge phase (R7-proven, 2 edges/thread) ----
    {
        const float gb = *gamma_b;
        const float gp = *gamma_p;
        const float w0 = 1.f / (1.f + __expf(gp - gb));
        const float w1 = 1.f - w0;

        const int n_half = n_edges >> 1;
        const int stride = gridDim.x * blockDim.x;
        const int gid    = blockIdx.x * blockDim.x + tid;

        const int2* src2 = (const int2*)src;
        const int2* dst2 = (const int2*)dst;
        float2*     out2 = (float2*)out;

        for (int i = gid; i < n_half; i += stride) {
            const int2 s = src2[i];
            const int2 d = dst2[i];
            const uint2 ts0 = tab8[s.x];
            const uint2 td0 = tab8[d.x];
            const uint2 ts1 = tab8[s.y];
            const uint2 td1 = tab8[d.y];
            float2 r;
            r.x = edge_score8(ts0, td0, w0, w1);
            r.y = edge_score8(ts1, td1, w0, w1);
            out2[i] = r;
        }
        const int tail_base = n_half << 1;
        for (int e = tail_base + gid; e < n_edges; e += stride) {
            out[e] = edge_score8(tab8[src[e]], tab8[dst[e]], w0, w1);
        }
    }
}

extern "C" void kernel_launch(void* const* d_in, const int* in_sizes, int n_in,
                              void* d_out, int out_size, void* d_ws, size_t ws_size,
                              hipStream_t stream) {
    const float* z_beh  = (const float*)d_in[0];
    const float* z_pref = (const float*)d_in[1];
    const float* W_b    = (const float*)d_in[2];
    const float* W_p    = (const float*)d_in[3];
    const float* a_b    = (const float*)d_in[4];
    const float* a_p    = (const float*)d_in[5];
    const float* g_b    = (const float*)d_in[6];
    const float* g_p    = (const float*)d_in[7];
    const int*   ei     = (const int*)d_in[8];   // [2, E] int32

    const int n_nodes = in_sizes[0] / 128;
    const int n_edges = in_sizes[8] / 2;

    unsigned* ws_barrier = (unsigned*)d_ws;                    // [0, 2 KB)
    float*    vws  = (float*)((char*)d_ws + 4096);             // 512 floats
    uint2*    tab8 = (uint2*)((char*)d_ws + 8192);             // n_nodes * 8 B

    // zero barrier counters every launch (graph-legal, deterministic replays)
    hipMemsetAsync(d_ws, 0, 2048, stream);

    fused_all_kernel<<<NBLOCKS, 256, 0, stream>>>(
        W_b, W_p, a_b, a_p,
        (const f32x4*)z_beh, (const f32x4*)z_pref,
        ei, ei + n_edges, g_b, g_p,
        (float*)d_out, ws_barrier, vws, tab8, n_nodes, n_edges);
}

// Round 10
// 36.493 us; speedup vs baseline: 15.4799x; 15.4799x over previous
//
#include <hip/hip_runtime.h>
#include <hip/hip_bf16.h>
#include <stdint.h>

#define NEG_SLOPE 0.2f

typedef float f32x4 __attribute__((ext_vector_type(4)));

// bf16 helpers (RTN-even pack, shift-unpack)
__device__ __forceinline__ unsigned f2bf(float f) {
    unsigned u = __float_as_uint(f);
    return (u + 0x7FFFu + ((u >> 16) & 1u)) >> 16;
}
__device__ __forceinline__ float bf2f(unsigned h) {
    return __uint_as_float(h << 16);
}

// global->LDS DMA: 16 B per lane, one call = 1 KB per wave, fire-and-forget.
__device__ __forceinline__ void dma16(const void* g, void* l) {
    __builtin_amdgcn_global_load_lds(
        (const __attribute__((address_space(1))) unsigned int*)g,
        (__attribute__((address_space(3))) unsigned int*)l,
        16, 0, 0);
}

// ---------------------------------------------------------------------------
// Node kernel, DMA-streaming version.
//  - per block: v-fold prologue into LDS (R6-proven), one __syncthreads.
//  - hot loop per WAVE (wave-private LDS, no barriers): 8 nodes/iter.
//    stage next tile (8 x global_load_lds of 1KB: z_beh rows then z_pref rows)
//    -> s_waitcnt vmcnt(8) (counted: waits only the PREVIOUS tile's DMAs)
//    -> consume current tile from LDS -> bf16 pack store.
//  - lane mapping: lane = ch*32 + n*4 + comp*2 + half
//    thread dots 64 floats (its half-row) with v[ch*2+comp], combines halves
//    with one shfl_xor(1).
//  - LDS reads iterate slots in (m ^ row)-order to spread banks (~4-way max;
//    LDS is far under budget here so this is belt-and-braces).
// ---------------------------------------------------------------------------
__global__ void __launch_bounds__(256, 2) node_scores_kernel(
        const float* __restrict__ W_b,
        const float* __restrict__ W_p,
        const float* __restrict__ a_b,
        const float* __restrict__ a_p,
        const char*  __restrict__ zb,    // z_beh  as bytes [n_nodes*512]
        const char*  __restrict__ zp,    // z_pref as bytes
        uint2*       __restrict__ tab8,  // [n_nodes] 4 x bf16
        int n_nodes) {
    __shared__ float vsh[4][128];            // v1_b, v2_b, v1_p, v2_p
    __shared__ char  zbuf[4][2][8192];       // [wave][buf][2ch x 8 nodes x 512B]

    const int tid = threadIdx.x;

    // ---- v prologue: vsh[2ch+vi][p] = sum_d W_ch[d][p] * a_ch[vi*64+d] ----
    {
        const int p  = tid & 127;
        const int ch = tid >> 7;
        const float* W = ch ? W_p : W_b;
        const float* a = ch ? a_p : a_b;
        float acc1 = 0.f, acc2 = 0.f;
        #pragma unroll
        for (int d = 0; d < 64; ++d) {
            const float w = W[d * 128 + p];
            acc1 += w * a[d];
            acc2 += w * a[64 + d];
        }
        vsh[2 * ch + 0][p] = acc1;
        vsh[2 * ch + 1][p] = acc2;
    }
    __syncthreads();

    const int wv   = tid >> 6;
    const int lane = tid & 63;
    const int ch   = lane >> 5;        // channel: 0 = beh, 1 = pref
    const int n    = (lane >> 2) & 7;  // local node 0..7
    const int comp = (lane >> 1) & 1;  // 0: si (v1), 1: sj (v2)
    const int half = lane & 1;         // which 64-float half of the row
    const int srow = n * 2 + half;     // local half-row id within channel
    const int vec  = ch * 2 + comp;    // tab component index

    const float* vrow = &vsh[vec][half * 64];
    char* lb[2] = { &zbuf[wv][0][0], &zbuf[wv][1][0] };

    // per-lane fixed offsets for the 8 staging DMAs (k<4: z_beh, k>=4: z_pref)
    const int dma_rch  = (lane >> 4);          // row-within-quad 0..3
    const int dma_col  = (lane & 15) * 16;     // byte within 256B half-row

    const int nwaves = (gridDim.x * blockDim.x) >> 6;
    const int ntiles = (n_nodes + 7) >> 3;     // 8 nodes per tile
    const int wave   = (blockIdx.x * blockDim.x + tid) >> 6;

    if (wave >= ntiles) return;

    // stage tile `t` into buffer `b` (8 x 1KB coalesced DMA)
    auto stage = [&](int b, int t) {
        const size_t tb = (size_t)t * 4096;    // 8 nodes * 512 B
        #pragma unroll
        for (int k = 0; k < 8; ++k) {
            const char* gsrc = (k < 4) ? zb : zp;
            const size_t g = tb + (size_t)((k & 3) * 4 + dma_rch) * 256 + dma_col;
            dma16(gsrc + g, lb[b] + k * 1024);
        }
    };

    stage(0, wave);
    int buf = 0;
    for (int t = wave; t < ntiles; t += nwaves) {
        const int nx = t + nwaves;
        stage(buf ^ 1, (nx < ntiles) ? nx : t);   // clamped re-stage on tail
        asm volatile("s_waitcnt vmcnt(8)" ::: "memory");  // prev tile resident
        __builtin_amdgcn_sched_barrier(0);

        // ---- consume current buffer ----
        const char* zrow = lb[buf] + (ch * 16 + srow) * 256;
        f32x4 acc4 = {0.f, 0.f, 0.f, 0.f};
        #pragma unroll
        for (int m = 0; m < 16; ++m) {
            const int slot = m ^ srow;                       // bank spread
            const f32x4 z4 = *(const f32x4*)(zrow + slot * 16);
            const f32x4 v4 = *(const f32x4*)(vrow + slot * 4);
            acc4 += z4 * v4;
        }
        float acc = acc4.x + acc4.y + acc4.z + acc4.w;
        acc += __shfl_xor(acc, 1);                           // combine halves
        const int node = t * 8 + n;
        if (half == 0 && node < n_nodes) {
            unsigned short* t16 = (unsigned short*)&tab8[node];
            t16[vec] = (unsigned short)f2bf(acc);
        }
        buf ^= 1;
    }
}

// ---------------------------------------------------------------------------
// Edge kernel — unchanged from R7 (2 edges/thread, 8 B bf16x4 gathers).
// ---------------------------------------------------------------------------
__device__ __forceinline__ float lrelu(float x) {
    return x >= 0.f ? x : NEG_SLOPE * x;
}

__device__ __forceinline__ float edge_score8(const uint2 ts, const uint2 td,
                                             float w0, float w1) {
    const float s_ib = bf2f(ts.x & 0xFFFFu), s_jb = bf2f(ts.x >> 16);
    const float s_ip = bf2f(ts.y & 0xFFFFu), s_jp = bf2f(ts.y >> 16);
    const float d_ib = bf2f(td.x & 0xFFFFu), d_jb = bf2f(td.x >> 16);
    const float d_ip = bf2f(td.y & 0xFFFFu), d_jp = bf2f(td.y >> 16);
    const float sb = 0.5f * (lrelu(s_ib + d_jb) + lrelu(d_ib + s_jb));
    const float sp = 0.5f * (lrelu(s_ip + d_jp) + lrelu(d_ip + s_jp));
    const float sc = w0 * sb + w1 * sp;            // TAU_MRF == 1
    return 1.f / (1.f + __expf(-sc));
}

__global__ void __launch_bounds__(256) edge_scores_kernel(
        const int*   __restrict__ src,
        const int*   __restrict__ dst,
        const uint2* __restrict__ tab8,
        const float* __restrict__ gamma_b,
        const float* __restrict__ gamma_p,
        float*       __restrict__ out,
        int n_edges) {
    const float gb = *gamma_b;
    const float gp = *gamma_p;
    const float w0 = 1.f / (1.f + __expf(gp - gb));  // softmax over 2 logits
    const float w1 = 1.f - w0;

    const int n_half = n_edges >> 1;
    const int stride = gridDim.x * blockDim.x;
    const int gid    = blockIdx.x * blockDim.x + threadIdx.x;

    const int2* src2 = (const int2*)src;
    const int2* dst2 = (const int2*)dst;
    float2*     out2 = (float2*)out;

    for (int i = gid; i < n_half; i += stride) {
        const int2 s = src2[i];
        const int2 d = dst2[i];
        const uint2 ts0 = tab8[s.x];
        const uint2 td0 = tab8[d.x];
        const uint2 ts1 = tab8[s.y];
        const uint2 td1 = tab8[d.y];
        float2 r;
        r.x = edge_score8(ts0, td0, w0, w1);
        r.y = edge_score8(ts1, td1, w0, w1);
        out2[i] = r;
    }
    const int tail_base = n_half << 1;
    for (int e = tail_base + gid; e < n_edges; e += stride) {
        out[e] = edge_score8(tab8[src[e]], tab8[dst[e]], w0, w1);
    }
}

extern "C" void kernel_launch(void* const* d_in, const int* in_sizes, int n_in,
                              void* d_out, int out_size, void* d_ws, size_t ws_size,
                              hipStream_t stream) {
    const float* z_beh  = (const float*)d_in[0];
    const float* z_pref = (const float*)d_in[1];
    const float* W_b    = (const float*)d_in[2];
    const float* W_p    = (const float*)d_in[3];
    const float* a_b    = (const float*)d_in[4];
    const float* a_p    = (const float*)d_in[5];
    const float* g_b    = (const float*)d_in[6];
    const float* g_p    = (const float*)d_in[7];
    const int*   ei     = (const int*)d_in[8];   // [2, E] int32

    const int n_nodes = in_sizes[0] / 128;
    const int n_edges = in_sizes[8] / 2;

    uint2* tab8 = (uint2*)d_ws;                  // n_nodes * 8 B

    // 512 blocks x 256 thr = 2048 waves; 2 blocks/CU (66KB LDS each)
    node_scores_kernel<<<512, 256, 0, stream>>>(
        W_b, W_p, a_b, a_p,
        (const char*)z_beh, (const char*)z_pref, tab8, n_nodes);

    const int n_half = n_edges >> 1;
    int eblocks = (n_half + 255) / 256;
    if (eblocks > 4096) eblocks = 4096;
    if (eblocks < 1) eblocks = 1;
    edge_scores_kernel<<<eblocks, 256, 0, stream>>>(
        ei, ei + n_edges, tab8, g_b, g_p, (float*)d_out, n_edges);
}

// Round 12
// 36.484 us; speedup vs baseline: 15.4840x; 1.0003x over previous
//
#include <hip/hip_runtime.h>
#include <hip/hip_bf16.h>

#define NEG_SLOPE 0.2f

typedef float f32x4 __attribute__((ext_vector_type(4)));
typedef int   i32x4 __attribute__((ext_vector_type(4)));

// ---------------------------------------------------------------------------
// Folded 64-lane reduction (6 shuffles) — proven R5.
// ---------------------------------------------------------------------------
__device__ __forceinline__ float fold_reduce(float sib, float sjb,
                                             float sip, float sjp,
                                             bool hiB, bool hiJ) {
    float g1 = hiB ? sib : sip;
    float r1 = __shfl_xor(g1, 16);
    float acc_i = (hiB ? sip : sib) + r1;
    float g2 = hiB ? sjb : sjp;
    float r2 = __shfl_xor(g2, 16);
    float acc_j = (hiB ? sjp : sjb) + r2;
    float g3 = hiJ ? acc_i : acc_j;
    float r3 = __shfl_xor(g3, 8);
    float acc = (hiJ ? acc_j : acc_i) + r3;
    acc += __shfl_xor(acc, 4);
    acc += __shfl_xor(acc, 2);
    acc += __shfl_xor(acc, 1);
    return acc;
}

__device__ __forceinline__ float dot4(const f32x4 z, const f32x4 v) {
    return z.x * v.x + z.y * v.y + z.z * v.z + z.w * v.w;
}

// ---------------------------------------------------------------------------
// Fused node kernel — EXACT R6 structure (measured best, 36.1 us total).
// 512 blocks x 1024 threads (2 blocks/CU), v-fold prologue in LDS,
// wave = 2 nodes/iter, 2-pair unroll, fp32 float4-equivalent tab stores.
// ---------------------------------------------------------------------------
__global__ void __launch_bounds__(1024) fused_node_kernel(
        const float* __restrict__ W_b,
        const float* __restrict__ W_p,
        const float* __restrict__ a_b,
        const float* __restrict__ a_p,
        const f32x4* __restrict__ zb4,
        const f32x4* __restrict__ zp4,
        float*       __restrict__ tab,   // float view of [n_nodes][4]
        int n_nodes) {
    __shared__ float vsh[4][128];   // v1_b, v2_b, v1_p, v2_p
    __shared__ float psh[1024];

    const int tid = threadIdx.x;
    {   // prologue: vsh[vec][p] = sum_d W_ch[d][p] * a_ch[aoff + d]
        const int q   = tid >> 9;        // d-half (0: d<32, 1: d>=32)
        const int r   = tid & 511;       // output index (vec*128 + p)
        const int vec = r >> 7;
        const int p   = r & 127;
        const float* W = (vec >= 2) ? W_p : W_b;
        const float* a = ((vec >= 2) ? a_p : a_b) + (vec & 1) * 64 + 32 * q;
        const float* Wc = W + (32 * q) * 128 + p;
        float acc = 0.f;
        #pragma unroll
        for (int k = 0; k < 32; ++k)
            acc += Wc[k * 128] * a[k];
        psh[tid] = acc;
    }
    __syncthreads();
    if (tid < 512)
        vsh[tid >> 7][tid & 127] = psh[tid] + psh[512 + tid];
    __syncthreads();

    const int lane = tid & 63;
    const int h    = lane >> 5;                 // which node of the pair
    const int c    = lane & 31;                 // f32x4 column group
    const int wave   = (blockIdx.x * blockDim.x + tid) >> 6;
    const int nwaves = (gridDim.x * blockDim.x) >> 6;   // 8192
    const int npairs = (n_nodes + 1) >> 1;

    const f32x4 v1b = *reinterpret_cast<const f32x4*>(&vsh[0][4 * c]);
    const f32x4 v2b = *reinterpret_cast<const f32x4*>(&vsh[1][4 * c]);
    const f32x4 v1p = *reinterpret_cast<const f32x4*>(&vsh[2][4 * c]);
    const f32x4 v2p = *reinterpret_cast<const f32x4*>(&vsh[3][4 * c]);

    const bool hiB = (c & 16) != 0;
    const bool hiJ = (c & 8)  != 0;
    const bool wr  = (c & 7) == 0;
    const int  comp = c >> 3;

    for (int pr = wave; pr < npairs; pr += 2 * nwaves) {
        const int pr2 = pr + nwaves;
        int node1 = 2 * pr + h;
        const bool valid1 = node1 < n_nodes;
        if (!valid1) node1 = n_nodes - 1;
        const f32x4 zb1 = zb4[(size_t)node1 * 32 + c];
        const f32x4 zp1 = zp4[(size_t)node1 * 32 + c];
        int node2 = 2 * pr2 + h;
        const bool run2 = pr2 < npairs;
        bool valid2 = run2 && (node2 < n_nodes);
        if (!valid2) node2 = n_nodes - 1;
        const f32x4 zb2 = zb4[(size_t)node2 * 32 + c];
        const f32x4 zp2 = zp4[(size_t)node2 * 32 + c];

        float acc1 = fold_reduce(dot4(zb1, v1b), dot4(zb1, v2b),
                                 dot4(zp1, v1p), dot4(zp1, v2p), hiB, hiJ);
        if (wr && valid1) tab[(size_t)node1 * 4 + comp] = acc1;

        float acc2 = fold_reduce(dot4(zb2, v1b), dot4(zb2, v2b),
                                 dot4(zp2, v1p), dot4(zp2, v2p), hiB, hiJ);
        if (wr && valid2) tab[(size_t)node2 * 4 + comp] = acc2;
    }
}

// ---------------------------------------------------------------------------
// Edge kernel — 4 edges/thread: int4 index loads (16 B/lane), 8 independent
// tab gathers issued before any compute, float4 output store.
// ---------------------------------------------------------------------------
__device__ __forceinline__ float lrelu(float x) {
    return x >= 0.f ? x : NEG_SLOPE * x;
}

__device__ __forceinline__ float edge_score(const f32x4 ts, const f32x4 td,
                                            float w0, float w1) {
    const float sb = 0.5f * (lrelu(ts.x + td.y) + lrelu(td.x + ts.y));
    const float sp = 0.5f * (lrelu(ts.z + td.w) + lrelu(td.z + ts.w));
    const float sc = w0 * sb + w1 * sp;            // TAU_MRF == 1
    return 1.f / (1.f + __expf(-sc));
}

__global__ void __launch_bounds__(256) edge_scores_kernel(
        const int*   __restrict__ src,
        const int*   __restrict__ dst,
        const f32x4* __restrict__ tab,
        const float* __restrict__ gamma_b,
        const float* __restrict__ gamma_p,
        float*       __restrict__ out,
        int n_edges) {
    const float gb = *gamma_b;
    const float gp = *gamma_p;
    const float w0 = 1.f / (1.f + __expf(gp - gb));  // softmax over 2 logits
    const float w1 = 1.f - w0;

    const int n_quads = n_edges >> 2;
    const int stride  = gridDim.x * blockDim.x;
    const int gid     = blockIdx.x * blockDim.x + threadIdx.x;

    const i32x4* src4 = (const i32x4*)src;
    const i32x4* dst4 = (const i32x4*)dst;
    f32x4*       out4 = (f32x4*)out;

    for (int i = gid; i < n_quads; i += stride) {
        const i32x4 s = src4[i];
        const i32x4 d = dst4[i];
        // issue all 8 gathers before any arithmetic (8-deep MLP)
        const f32x4 ts0 = tab[s.x];
        const f32x4 td0 = tab[d.x];
        const f32x4 ts1 = tab[s.y];
        const f32x4 td1 = tab[d.y];
        const f32x4 ts2 = tab[s.z];
        const f32x4 td2 = tab[d.z];
        const f32x4 ts3 = tab[s.w];
        const f32x4 td3 = tab[d.w];
        f32x4 r;
        r.x = edge_score(ts0, td0, w0, w1);
        r.y = edge_score(ts1, td1, w0, w1);
        r.z = edge_score(ts2, td2, w0, w1);
        r.w = edge_score(ts3, td3, w0, w1);
        out4[i] = r;
    }
    // tail (n_edges % 4) — unused for E = 1e6 but kept for safety
    const int tail_base = n_quads << 2;
    for (int e = tail_base + gid; e < n_edges; e += stride) {
        const f32x4 ts = tab[src[e]];
        const f32x4 td = tab[dst[e]];
        out[e] = edge_score(ts, td, w0, w1);
    }
}

extern "C" void kernel_launch(void* const* d_in, const int* in_sizes, int n_in,
                              void* d_out, int out_size, void* d_ws, size_t ws_size,
                              hipStream_t stream) {
    const float* z_beh  = (const float*)d_in[0];
    const float* z_pref = (const float*)d_in[1];
    const float* W_b    = (const float*)d_in[2];
    const float* W_p    = (const float*)d_in[3];
    const float* a_b    = (const float*)d_in[4];
    const float* a_p    = (const float*)d_in[5];
    const float* g_b    = (const float*)d_in[6];
    const float* g_p    = (const float*)d_in[7];
    const int*   ei     = (const int*)d_in[8];   // [2, E] int32

    const int n_nodes = in_sizes[0] / 128;
    const int n_edges = in_sizes[8] / 2;

    float* tab = (float*)d_ws;                   // n_nodes * 4 floats

    // 512 blocks x 1024 threads: exactly resident, 8192 waves (R6-proven)
    fused_node_kernel<<<512, 1024, 0, stream>>>(
        W_b, W_p, a_b, a_p,
        (const f32x4*)z_beh, (const f32x4*)z_pref, tab, n_nodes);

    const int n_quads = n_edges >> 2;
    int eblocks = (n_quads + 255) / 256;
    if (eblocks > 4096) eblocks = 4096;
    if (eblocks < 1) eblocks = 1;
    edge_scores_kernel<<<eblocks, 256, 0, stream>>>(
        ei, ei + n_edges, (const f32x4*)tab, g_b, g_p, (float*)d_out, n_edges);
}